// Round 2
// baseline (1311.523 us; speedup 1.0000x reference)
//
#include <hip/hip_runtime.h>

// MAB block (all fp32 I/O): Qp=Q@Wq+bq, Kp=K@Wk+bk, Vp=K@Wv+bv (H=4, DH=64)
// attn = softmax(Qp Kp^T / 8) Vp ; O = LN(Qp + attn) ; out = LN(O + FFN(O))

typedef float fx4 __attribute__((ext_vector_type(4)));

#define BB  4
#define NQL 2048
#define NKL 2048
#define DD  256
#define HH  4
#define DHH 64

// ---------------------------------------------------------------------------
// GEMM: C[M,256] = A[M,256] @ W[256,256] + bias.  1 wave/block, 4 rows/block.
// Lane owns cols lane*4..+3; W row load is coalesced fx4 (16B/lane = full row).
// ---------------------------------------------------------------------------
__global__ __launch_bounds__(64) void gemm_f32(
        const float* __restrict__ A, const float* __restrict__ W,
        const float* __restrict__ bias, float* __restrict__ C) {
    __shared__ float xs[4 * 256];
    const int lane = threadIdx.x;
    const int r0 = blockIdx.x * 4;
    const fx4* A4 = (const fx4*)(A + (size_t)r0 * DD);
#pragma unroll
    for (int j = 0; j < 4; ++j) { int c = lane + 64 * j; *(fx4*)(xs + c * 4) = A4[c]; }
    __syncthreads();
    float acc[4][4] = {};
    const fx4* W4 = (const fx4*)W;
#pragma unroll 4
    for (int k = 0; k < 256; ++k) {
        fx4 wv = W4[k * 64 + lane];
#pragma unroll
        for (int r = 0; r < 4; ++r) {
            float x = xs[r * 256 + k];
            acc[r][0] += x*wv[0]; acc[r][1] += x*wv[1];
            acc[r][2] += x*wv[2]; acc[r][3] += x*wv[3];
        }
    }
    fx4 bv = ((const fx4*)bias)[lane];
#pragma unroll
    for (int r = 0; r < 4; ++r) {
        fx4 o;
#pragma unroll
        for (int i = 0; i < 4; ++i) o[i] = acc[r][i] + bv[i];
        ((fx4*)(C + (size_t)(r0 + r) * DD))[lane] = o;
    }
}

// FFN1: C = relu(A@W1 + b1)
__global__ __launch_bounds__(64) void gemm_relu(
        const float* __restrict__ A, const float* __restrict__ W,
        const float* __restrict__ bias, float* __restrict__ C) {
    __shared__ float xs[4 * 256];
    const int lane = threadIdx.x;
    const int r0 = blockIdx.x * 4;
    const fx4* A4 = (const fx4*)(A + (size_t)r0 * DD);
#pragma unroll
    for (int j = 0; j < 4; ++j) { int c = lane + 64 * j; *(fx4*)(xs + c * 4) = A4[c]; }
    __syncthreads();
    float acc[4][4] = {};
    const fx4* W4 = (const fx4*)W;
#pragma unroll 4
    for (int k = 0; k < 256; ++k) {
        fx4 wv = W4[k * 64 + lane];
#pragma unroll
        for (int r = 0; r < 4; ++r) {
            float x = xs[r * 256 + k];
            acc[r][0] += x*wv[0]; acc[r][1] += x*wv[1];
            acc[r][2] += x*wv[2]; acc[r][3] += x*wv[3];
        }
    }
    fx4 bv = ((const fx4*)bias)[lane];
#pragma unroll
    for (int r = 0; r < 4; ++r) {
        fx4 o;
#pragma unroll
        for (int i = 0; i < 4; ++i) o[i] = fmaxf(acc[r][i] + bv[i], 0.0f);
        ((fx4*)(C + (size_t)(r0 + r) * DD))[lane] = o;
    }
}

// FFN2 + residual + LayerNorm fused: out = LN(R + A@W2 + b2)
__global__ __launch_bounds__(64) void gemm_ffn2_ln(
        const float* __restrict__ A, const float* __restrict__ W,
        const float* __restrict__ bias, const float* __restrict__ R,
        const float* __restrict__ g, const float* __restrict__ be,
        float* __restrict__ out) {
    __shared__ float xs[4 * 256];
    const int lane = threadIdx.x;
    const int r0 = blockIdx.x * 4;
    const fx4* A4 = (const fx4*)(A + (size_t)r0 * DD);
#pragma unroll
    for (int j = 0; j < 4; ++j) { int c = lane + 64 * j; *(fx4*)(xs + c * 4) = A4[c]; }
    __syncthreads();
    float acc[4][4] = {};
    const fx4* W4 = (const fx4*)W;
#pragma unroll 4
    for (int k = 0; k < 256; ++k) {
        fx4 wv = W4[k * 64 + lane];
#pragma unroll
        for (int r = 0; r < 4; ++r) {
            float x = xs[r * 256 + k];
            acc[r][0] += x*wv[0]; acc[r][1] += x*wv[1];
            acc[r][2] += x*wv[2]; acc[r][3] += x*wv[3];
        }
    }
    fx4 bv = ((const fx4*)bias)[lane];
    fx4 gv = ((const fx4*)g)[lane];
    fx4 ev = ((const fx4*)be)[lane];
#pragma unroll
    for (int r = 0; r < 4; ++r) {
        fx4 rv = ((const fx4*)(R + (size_t)(r0 + r) * DD))[lane];
        fx4 v;
#pragma unroll
        for (int i = 0; i < 4; ++i) v[i] = acc[r][i] + bv[i] + rv[i];
        float s1 = v[0]+v[1]+v[2]+v[3];
        float s2 = v[0]*v[0]+v[1]*v[1]+v[2]*v[2]+v[3]*v[3];
#pragma unroll
        for (int off = 32; off >= 1; off >>= 1) {
            s1 += __shfl_xor(s1, off); s2 += __shfl_xor(s2, off);
        }
        float mean = s1 * (1.0f/256.0f);
        float var  = s2 * (1.0f/256.0f) - mean * mean;
        float rstd = rsqrtf(var + 1e-5f);
        fx4 o;
#pragma unroll
        for (int i = 0; i < 4; ++i) o[i] = (v[i]-mean)*rstd*gv[i] + ev[i];
        ((fx4*)(out + (size_t)(r0 + r) * DD))[lane] = o;
    }
}

// standalone row LayerNorm: Y = LN(X)*g+be
__global__ __launch_bounds__(64) void ln_rows(
        const float* __restrict__ X, const float* __restrict__ g,
        const float* __restrict__ be, float* __restrict__ Y) {
    const int lane = threadIdx.x;
    const size_t row = blockIdx.x;
    fx4 v = ((const fx4*)(X + row * DD))[lane];
    float s1 = v[0]+v[1]+v[2]+v[3];
    float s2 = v[0]*v[0]+v[1]*v[1]+v[2]*v[2]+v[3]*v[3];
#pragma unroll
    for (int off = 32; off >= 1; off >>= 1) {
        s1 += __shfl_xor(s1, off); s2 += __shfl_xor(s2, off);
    }
    float mean = s1 * (1.0f/256.0f);
    float var  = s2 * (1.0f/256.0f) - mean * mean;
    float rstd = rsqrtf(var + 1e-5f);
    fx4 gv = ((const fx4*)g)[lane];
    fx4 ev = ((const fx4*)be)[lane];
    fx4 o;
#pragma unroll
    for (int i = 0; i < 4; ++i) o[i] = (v[i]-mean)*rstd*gv[i] + ev[i];
    ((fx4*)(Y + row * DD))[lane] = o;
}

// ---------------------------------------------------------------------------
// Attention: thread owns one q-row (q + acc in registers), flash online
// softmax. Block = 128 thr = 2 waves splitting K (1024 keys each), per-wave
// private K/V LDS tiles (32 keys x 64d), broadcast LDS reads (conflict-free).
// In-block merge of the 2 K-partials; writes Opre = Qp + attn (residual).
// ---------------------------------------------------------------------------
__global__ __launch_bounds__(128, 2) void attn(
        const float* __restrict__ Qp, const float* __restrict__ Kp,
        const float* __restrict__ Vp, float* __restrict__ Opre) {
    // LDS: tiles [0,8192) (2 waves x (2048 K + 2048 V)); reused after barrier
    // as merge area accL[2][64][65] = [0,8320); stats at [8320,8768).
    __shared__ float smem[8320 + 448];
    const int tid  = threadIdx.x;
    const int lane = tid & 63;
    const int w    = tid >> 6;
    const int qc = blockIdx.x & 31;
    const int h  = (blockIdx.x >> 5) & 3;
    const int b  = blockIdx.x >> 7;
    const int qrow = qc * 64 + lane;

    fx4 q4[16];
    const fx4* Q4 = (const fx4*)(Qp + (size_t)(b * NQL + qrow) * DD + h * DHH);
#pragma unroll
    for (int j = 0; j < 16; ++j) q4[j] = Q4[j];
    fx4 acc4[16];
#pragma unroll
    for (int i = 0; i < 16; ++i) acc4[i] = (fx4){0.f,0.f,0.f,0.f};
    float m = -1e30f, l = 0.0f;

    float* ksm = smem + w * 4096;
    float* vsm = ksm + 2048;
    const int k0 = w * 1024;

    for (int t = 0; t < 32; ++t) {
        const int kt = k0 + t * 32;
        const fx4* K4 = (const fx4*)(Kp + (size_t)(b * NKL + kt) * DD + h * DHH);
        const fx4* V4 = (const fx4*)(Vp + (size_t)(b * NKL + kt) * DD + h * DHH);
#pragma unroll
        for (int j = 0; j < 8; ++j) {
            int c = lane + 64 * j;           // 512 fx4 chunks = 32 keys x 64d
            int key = c >> 4, d4 = c & 15;
            *(fx4*)(ksm + key * 64 + d4 * 4) = K4[key * 64 + d4];  // row stride 64 fx4
            *(fx4*)(vsm + key * 64 + d4 * 4) = V4[key * 64 + d4];
        }
        // wave-private tile: in-wave lgkmcnt ordering suffices, no barrier
        float s[32];
        const fx4* ks4 = (const fx4*)ksm;
#pragma unroll
        for (int key = 0; key < 32; ++key) {
            fx4 sa = (fx4){0.f,0.f,0.f,0.f};
#pragma unroll
            for (int d4 = 0; d4 < 16; ++d4) sa += q4[d4] * ks4[key * 16 + d4];
            s[key] = (sa[0]+sa[1]+sa[2]+sa[3]) * 0.125f;
        }
        float mn = m;
#pragma unroll
        for (int key = 0; key < 32; ++key) mn = fmaxf(mn, s[key]);
        float al = __expf(m - mn);
        m = mn; l *= al;
#pragma unroll
        for (int d4 = 0; d4 < 16; ++d4) acc4[d4] *= al;
        const fx4* vs4 = (const fx4*)vsm;
#pragma unroll
        for (int key = 0; key < 32; ++key) {
            float p = __expf(s[key] - m);
            l += p;
#pragma unroll
            for (int d4 = 0; d4 < 16; ++d4) acc4[d4] += p * vs4[key * 16 + d4];
        }
    }
    __syncthreads();                       // all waves done with tile region
    {   // write partial (unnormalized acc, m, l); accL stride 65 -> no conflicts
        float* rowp = smem + (w * 64 + lane) * 65;
#pragma unroll
        for (int d4 = 0; d4 < 16; ++d4)
#pragma unroll
            for (int i = 0; i < 4; ++i) rowp[d4 * 4 + i] = acc4[d4][i];
        smem[8320 +       w * 64 + lane] = m;   // m: [8320,8448)
        smem[8448 +       w * 64 + lane] = l;   // l: [8448,8576)
    }
    __syncthreads();
    if (tid < 64) {                        // per-row merge coefficients
        int r = tid;
        float m0 = smem[8320 + r], m1 = smem[8384 + r];
        float l0 = smem[8448 + r], l1 = smem[8512 + r];
        float M  = fmaxf(m0, m1);
        float a0 = __expf(m0 - M), a1 = __expf(m1 - M);
        float L  = a0 * l0 + a1 * l1;
        smem[8576 + r] = a0;
        smem[8640 + r] = a1;
        smem[8704 + r] = 1.0f / L;
    }
    __syncthreads();
    {   // merge + residual: thread (w,lane) -> row=lane, d-half = w*32..+32
        int r = lane;
        float invl = smem[8704 + r];
        fx4 o[8];
#pragma unroll
        for (int i = 0; i < 8; ++i) o[i] = (fx4){0.f,0.f,0.f,0.f};
#pragma unroll
        for (int p = 0; p < 2; ++p) {
            float ap = smem[8576 + p * 64 + r];
            const float* rowp = smem + (p * 64 + r) * 65 + w * 32;
#pragma unroll
            for (int i = 0; i < 8; ++i)
#pragma unroll
                for (int jj = 0; jj < 4; ++jj) o[i][jj] += ap * rowp[i * 4 + jj];
        }
        const size_t obase = (size_t)(b * NQL + qc * 64 + r) * DD + h * DHH + w * 32;
        fx4* O4 = (fx4*)(Opre + obase);
#pragma unroll
        for (int i = 0; i < 8; ++i) O4[i] = o[i] * invl + q4[w * 8 + i];
    }
}

extern "C" void kernel_launch(void* const* d_in, const int* in_sizes, int n_in,
                              void* d_out, int out_size, void* d_ws, size_t ws_size,
                              hipStream_t stream) {
    (void)in_sizes; (void)n_in; (void)out_size; (void)ws_size;
    const float* Q     = (const float*)d_in[0];
    const float* K     = (const float*)d_in[1];
    const float* Wq    = (const float*)d_in[2];
    const float* bq    = (const float*)d_in[3];
    const float* Wk    = (const float*)d_in[4];
    const float* bk    = (const float*)d_in[5];
    const float* Wv    = (const float*)d_in[6];
    const float* bv    = (const float*)d_in[7];
    const float* W1    = (const float*)d_in[8];
    const float* b1    = (const float*)d_in[9];
    const float* W2    = (const float*)d_in[10];
    const float* b2    = (const float*)d_in[11];
    const float* g0    = (const float*)d_in[12];
    const float* beta0 = (const float*)d_in[13];
    const float* g1    = (const float*)d_in[14];
    const float* beta1 = (const float*)d_in[15];

    // Workspace (32 MiB, fp32), with stream-ordered aliasing:
    //   [0,8)  MiB: Qp, later O (ln_rows runs after attn's last Qp read)
    //   [8,16) MiB: Kp, later H1 (ffn1 runs after attn's last Kp read)
    //   [16,24)MiB: Vp
    //   [24,32)MiB: Opre
    char* ws = (char*)d_ws;
    float* Qp   = (float*)(ws);
    float* Kp   = (float*)(ws + (8u  << 20));
    float* Vp   = (float*)(ws + (16u << 20));
    float* Opre = (float*)(ws + (24u << 20));
    float* O    = Qp;
    float* H1   = Kp;
    float* out  = (float*)d_out;

    const int M = BB * NQL;                       // 8192 rows
    gemm_f32<<<M / 4, 64, 0, stream>>>(Q, Wq, bq, Qp);
    gemm_f32<<<M / 4, 64, 0, stream>>>(K, Wk, bk, Kp);
    gemm_f32<<<M / 4, 64, 0, stream>>>(K, Wv, bv, Vp);
    attn<<<BB * HH * (NQL / 64), 128, 0, stream>>>(Qp, Kp, Vp, Opre);
    ln_rows<<<M, 64, 0, stream>>>(Opre, g0, beta0, O);
    gemm_relu<<<M / 4, 64, 0, stream>>>(O, W1, b1, H1);
    gemm_ffn2_ln<<<M / 4, 64, 0, stream>>>(H1, W2, b2, O, g1, beta1, out);
}

// Round 3
// 291.192 us; speedup vs baseline: 4.5040x; 4.5040x over previous
//
#include <hip/hip_runtime.h>

// MAB block, MFMA bf16 version.
// Qp=Q@Wq+bq, Kp=K@Wk+bk, Vp=K@Wv+bv (bf16); VT = Vp^T per (b,h).
// attn = softmax(Qp Kp^T/8) Vp via 16x16x32 bf16 MFMA flash loop.
// Opre = attn + Qp ; O = LN(Opre) ; H1 = relu(O@W1+b1) bf16 ;
// G = H1@W2+b2 fp32 ; out = LN(O+G).

typedef float fx4 __attribute__((ext_vector_type(4)));
typedef short short8 __attribute__((ext_vector_type(8)));

#define BB  4
#define NN  2048
#define DD  256
#define HH  4
#define DHH 64

__device__ __forceinline__ float bf2f(unsigned short u) {
    union { unsigned int i; float f; } v; v.i = ((unsigned int)u) << 16; return v.f;
}
__device__ __forceinline__ unsigned short f2bf(float f) {
    union { float f; unsigned int i; } v; v.f = f;
    unsigned int r = v.i + 0x7FFF + ((v.i >> 16) & 1);   // RNE
    return (unsigned short)(r >> 16);
}

// ---------------------------------------------------------------------------
// Weight prep: WT[n][k] = bf16(W[k][n]) for the 5 weight matrices (256x256).
// grid (4,4,5), 256 thr. LDS tile transpose, pitch 73 to scramble banks.
// ---------------------------------------------------------------------------
__global__ __launch_bounds__(256) void wt_prep(
        const float* __restrict__ w0, const float* __restrict__ w1,
        const float* __restrict__ w2, const float* __restrict__ w3,
        const float* __restrict__ w4, unsigned short* __restrict__ dst) {
    __shared__ unsigned short T[64 * 73];
    const int tid = threadIdx.x;
    const int z = blockIdx.z;
    const float* W = (z == 0) ? w0 : (z == 1) ? w1 : (z == 2) ? w2 : (z == 3) ? w3 : w4;
    unsigned short* WT = dst + z * 65536;
    const int nb = blockIdx.x * 64, kb = blockIdx.y * 64;
    {
        int kl = tid >> 2, c0 = (tid & 3) * 16;
        const float* src = W + (size_t)(kb + kl) * DD + nb + c0;
#pragma unroll
        for (int i = 0; i < 16; ++i) T[kl * 73 + c0 + i] = f2bf(src[i]);
    }
    __syncthreads();
    {
        int nl = tid >> 2, k0 = (tid & 3) * 16;
        short8 o0, o1;
#pragma unroll
        for (int i = 0; i < 8; ++i) {
            o0[i] = (short)T[(k0 + i) * 73 + nl];
            o1[i] = (short)T[(k0 + 8 + i) * 73 + nl];
        }
        short8* d = (short8*)(WT + (size_t)(nb + nl) * DD + kb + k0);
        d[0] = o0; d[1] = o1;
    }
}

// ---------------------------------------------------------------------------
// V transpose: VT[(b*4+h)*64 + d][key] = Vp[b*2048+key][h*64+d]. grid(128,4).
// ---------------------------------------------------------------------------
__global__ __launch_bounds__(256) void vt_prep(
        const unsigned short* __restrict__ Vp, unsigned short* __restrict__ VT) {
    __shared__ unsigned short T[64 * 73];
    const int tid = threadIdx.x;
    const int hb = blockIdx.y;
    const int b = blockIdx.x >> 5;
    const int keyb = (blockIdx.x & 31) * 64;
    {
        int kl = tid >> 2, c0 = (tid & 3) * 16;
        const short8* src = (const short8*)(Vp + (size_t)(b * NN + keyb + kl) * DD + hb * DHH + c0);
        short8 v0 = src[0], v1 = src[1];
#pragma unroll
        for (int i = 0; i < 8; ++i) {
            T[kl * 73 + c0 + i]     = (unsigned short)v0[i];
            T[kl * 73 + c0 + 8 + i] = (unsigned short)v1[i];
        }
    }
    __syncthreads();
    {
        int dl = tid >> 2, k0 = (tid & 3) * 16;
        short8 o0, o1;
#pragma unroll
        for (int i = 0; i < 8; ++i) {
            o0[i] = (short)T[(k0 + i) * 73 + dl];
            o1[i] = (short)T[(k0 + 8 + i) * 73 + dl];
        }
        short8* d = (short8*)(VT + (size_t)((b * HH + hb) * DHH + dl) * NN + keyb + k0);
        d[0] = o0; d[1] = o1;
    }
}

// ---------------------------------------------------------------------------
// MFMA GEMM: C[8192,256] = A[8192,256] @ W + bias.  Block = 16 rows x 256
// cols, 4 waves (wave w owns cols w*64..+63).  A staged in LDS as bf16
// (pitch 264 u16); B-frags direct from WT (bf16, [n][k]).
// AIN: 0 = fp32 A, 1 = bf16 A.  EP: 0 = bias->bf16, 1 = relu->bf16, 2 = bias->f32.
// ---------------------------------------------------------------------------
template<int AIN, int EP>
__global__ __launch_bounds__(256) void gemm_mfma(
        const void* __restrict__ Ain, const unsigned short* __restrict__ WT,
        const float* __restrict__ bias, void* __restrict__ Cout) {
    __shared__ unsigned short As[16 * 264];
    const int tid = threadIdx.x;
    const int lane = tid & 63, w = tid >> 6;
    const int l15 = lane & 15, quad = lane >> 4;
    const int r0 = blockIdx.x * 16;
    {   // stage A tile (16 x 256) as bf16
        int row = tid >> 4, c0 = (tid & 15) * 16;
        short8 o0, o1;
        if (AIN == 0) {
            const fx4* s4 = (const fx4*)((const float*)Ain + (size_t)(r0 + row) * DD + c0);
            fx4 v0 = s4[0], v1 = s4[1], v2 = s4[2], v3 = s4[3];
#pragma unroll
            for (int i = 0; i < 4; ++i) {
                o0[i]     = (short)f2bf(v0[i]); o0[i + 4] = (short)f2bf(v1[i]);
                o1[i]     = (short)f2bf(v2[i]); o1[i + 4] = (short)f2bf(v3[i]);
            }
        } else {
            const short8* s8 = (const short8*)((const unsigned short*)Ain + (size_t)(r0 + row) * DD + c0);
            o0 = s8[0]; o1 = s8[1];
        }
        short8* d = (short8*)(As + row * 264 + c0);
        d[0] = o0; d[1] = o1;
    }
    __syncthreads();
    fx4 acc[4];
#pragma unroll
    for (int i = 0; i < 4; ++i) acc[i] = (fx4){0.f, 0.f, 0.f, 0.f};
#pragma unroll
    for (int kc = 0; kc < 8; ++kc) {
        short8 a = *(const short8*)(As + l15 * 264 + kc * 32 + 8 * quad);
#pragma unroll
        for (int dt = 0; dt < 4; ++dt) {
            short8 bfr = *(const short8*)(WT + (size_t)(w * 64 + dt * 16 + l15) * DD + kc * 32 + 8 * quad);
            acc[dt] = __builtin_amdgcn_mfma_f32_16x16x32_bf16(a, bfr, acc[dt], 0, 0, 0);
        }
    }
    float bv[4];
#pragma unroll
    for (int dt = 0; dt < 4; ++dt) bv[dt] = bias[w * 64 + dt * 16 + l15];
#pragma unroll
    for (int r = 0; r < 4; ++r) {
        const size_t grow = r0 + 4 * quad + r;
#pragma unroll
        for (int dt = 0; dt < 4; ++dt) {
            const int col = w * 64 + dt * 16 + l15;
            float v = acc[dt][r] + bv[dt];
            if (EP == 1) v = fmaxf(v, 0.0f);
            if (EP <= 1) ((unsigned short*)Cout)[grow * DD + col] = f2bf(v);
            else         ((float*)Cout)[grow * DD + col] = v;
        }
    }
}

// ---------------------------------------------------------------------------
// Flash attention, MFMA. Block = 64 q-rows (4 waves x 16), per (b,h,qtile).
// K-tiles of 64 keys; Q/K/V bf16; online softmax in C-layout; P via per-wave
// LDS round-trip to A-layout. Writes Opre = attn + Qp (fp32).
// ---------------------------------------------------------------------------
__global__ __launch_bounds__(256) void attn_mfma(
        const unsigned short* __restrict__ Qp, const unsigned short* __restrict__ Kp,
        const unsigned short* __restrict__ VT, float* __restrict__ Opre) {
    __shared__ unsigned short plds[4 * 16 * 72];
    const int tid = threadIdx.x;
    const int lane = tid & 63, w = tid >> 6;
    const int l15 = lane & 15, quad = lane >> 4;
    const int qc = blockIdx.x & 31;
    const int h  = (blockIdx.x >> 5) & 3;
    const int b  = blockIdx.x >> 7;
    const int qrow = qc * 64 + w * 16;

    short8 aq0, aq1;
    {
        const unsigned short* qptr = Qp + ((size_t)(b * NN + qrow + l15) * DD + h * DHH + 8 * quad);
        aq0 = *(const short8*)qptr;
        aq1 = *(const short8*)(qptr + 32);
    }
    fx4 od[4];
#pragma unroll
    for (int i = 0; i < 4; ++i) od[i] = (fx4){0.f, 0.f, 0.f, 0.f};
    float m[4], l[4];
#pragma unroll
    for (int r = 0; r < 4; ++r) { m[r] = -1e30f; l[r] = 0.0f; }

    unsigned short* pl = plds + w * (16 * 72);
    const unsigned short* kbase = Kp + ((size_t)(b * NN) * DD + h * DHH + 8 * quad);
    const unsigned short* vbase = VT + ((size_t)((b * HH + h) * DHH) * NN + 8 * quad);

    for (int t = 0; t < 32; ++t) {
        fx4 s[4];
#pragma unroll
        for (int j = 0; j < 4; ++j) {
            const unsigned short* kp = kbase + (size_t)(t * 64 + j * 16 + l15) * DD;
            short8 b0 = *(const short8*)kp;
            short8 b1 = *(const short8*)(kp + 32);
            fx4 a = (fx4){0.f, 0.f, 0.f, 0.f};
            a = __builtin_amdgcn_mfma_f32_16x16x32_bf16(aq0, b0, a, 0, 0, 0);
            a = __builtin_amdgcn_mfma_f32_16x16x32_bf16(aq1, b1, a, 0, 0, 0);
            s[j] = a * 0.125f;
        }
        float tm[4];
#pragma unroll
        for (int r = 0; r < 4; ++r)
            tm[r] = fmaxf(fmaxf(s[0][r], s[1][r]), fmaxf(s[2][r], s[3][r]));
#pragma unroll
        for (int r = 0; r < 4; ++r) {
            tm[r] = fmaxf(tm[r], __shfl_xor(tm[r], 1));
            tm[r] = fmaxf(tm[r], __shfl_xor(tm[r], 2));
            tm[r] = fmaxf(tm[r], __shfl_xor(tm[r], 4));
            tm[r] = fmaxf(tm[r], __shfl_xor(tm[r], 8));
        }
        float alpha[4];
#pragma unroll
        for (int r = 0; r < 4; ++r) {
            float mn = fmaxf(m[r], tm[r]);
            alpha[r] = __expf(m[r] - mn);
            m[r] = mn;
        }
#pragma unroll
        for (int dt = 0; dt < 4; ++dt)
#pragma unroll
            for (int r = 0; r < 4; ++r) od[dt][r] *= alpha[r];
        float tl[4] = {0.f, 0.f, 0.f, 0.f};
#pragma unroll
        for (int j = 0; j < 4; ++j)
#pragma unroll
            for (int r = 0; r < 4; ++r) {
                float p = __expf(s[j][r] - m[r]);
                s[j][r] = p;
                tl[r] += p;
            }
#pragma unroll
        for (int r = 0; r < 4; ++r) {
            tl[r] += __shfl_xor(tl[r], 1);
            tl[r] += __shfl_xor(tl[r], 2);
            tl[r] += __shfl_xor(tl[r], 4);
            tl[r] += __shfl_xor(tl[r], 8);
            l[r] = l[r] * alpha[r] + tl[r];
        }
        // P -> LDS (bf16), C-layout scatter; rows padded to 72 u16
#pragma unroll
        for (int j = 0; j < 4; ++j)
#pragma unroll
            for (int r = 0; r < 4; ++r)
                pl[(4 * quad + r) * 72 + j * 16 + l15] = f2bf(s[j][r]);
        __syncthreads();
        short8 ap0 = *(const short8*)(pl + l15 * 72 + 8 * quad);
        short8 ap1 = *(const short8*)(pl + l15 * 72 + 32 + 8 * quad);
#pragma unroll
        for (int dt = 0; dt < 4; ++dt) {
            const unsigned short* vp = vbase + (size_t)(dt * 16 + l15) * NN + t * 64;
            short8 bv0 = *(const short8*)vp;
            short8 bv1 = *(const short8*)(vp + 32);
            od[dt] = __builtin_amdgcn_mfma_f32_16x16x32_bf16(ap0, bv0, od[dt], 0, 0, 0);
            od[dt] = __builtin_amdgcn_mfma_f32_16x16x32_bf16(ap1, bv1, od[dt], 0, 0, 0);
        }
    }
#pragma unroll
    for (int r = 0; r < 4; ++r) {
        float inv = 1.0f / l[r];
        const size_t grow = b * NN + qrow + 4 * quad + r;
#pragma unroll
        for (int dt = 0; dt < 4; ++dt) {
            const int col = h * DHH + dt * 16 + l15;
            float v = od[dt][r] * inv + bf2f(Qp[grow * DD + col]);
            Opre[grow * DD + col] = v;
        }
    }
}

// row LayerNorm: Y = LN(X)*g+be (fp32)
__global__ __launch_bounds__(64) void ln_rows(
        const float* __restrict__ X, const float* __restrict__ g,
        const float* __restrict__ be, float* __restrict__ Y) {
    const int lane = threadIdx.x;
    const size_t row = blockIdx.x;
    fx4 v = ((const fx4*)(X + row * DD))[lane];
    float s1 = v[0]+v[1]+v[2]+v[3];
    float s2 = v[0]*v[0]+v[1]*v[1]+v[2]*v[2]+v[3]*v[3];
#pragma unroll
    for (int off = 32; off >= 1; off >>= 1) {
        s1 += __shfl_xor(s1, off); s2 += __shfl_xor(s2, off);
    }
    float mean = s1 * (1.0f/256.0f);
    float var  = s2 * (1.0f/256.0f) - mean * mean;
    float rstd = rsqrtf(var + 1e-5f);
    fx4 gv = ((const fx4*)g)[lane];
    fx4 ev = ((const fx4*)be)[lane];
    fx4 o;
#pragma unroll
    for (int i = 0; i < 4; ++i) o[i] = (v[i]-mean)*rstd*gv[i] + ev[i];
    ((fx4*)(Y + row * DD))[lane] = o;
}

// out = LN(X + Y)*g+be (fp32)
__global__ __launch_bounds__(64) void add_ln(
        const float* __restrict__ X, const float* __restrict__ Y,
        const float* __restrict__ g, const float* __restrict__ be,
        float* __restrict__ out) {
    const int lane = threadIdx.x;
    const size_t row = blockIdx.x;
    fx4 v = ((const fx4*)(X + row * DD))[lane] + ((const fx4*)(Y + row * DD))[lane];
    float s1 = v[0]+v[1]+v[2]+v[3];
    float s2 = v[0]*v[0]+v[1]*v[1]+v[2]*v[2]+v[3]*v[3];
#pragma unroll
    for (int off = 32; off >= 1; off >>= 1) {
        s1 += __shfl_xor(s1, off); s2 += __shfl_xor(s2, off);
    }
    float mean = s1 * (1.0f/256.0f);
    float var  = s2 * (1.0f/256.0f) - mean * mean;
    float rstd = rsqrtf(var + 1e-5f);
    fx4 gv = ((const fx4*)g)[lane];
    fx4 ev = ((const fx4*)be)[lane];
    fx4 o;
#pragma unroll
    for (int i = 0; i < 4; ++i) o[i] = (v[i]-mean)*rstd*gv[i] + ev[i];
    ((fx4*)(out + row * DD))[lane] = o;
}

extern "C" void kernel_launch(void* const* d_in, const int* in_sizes, int n_in,
                              void* d_out, int out_size, void* d_ws, size_t ws_size,
                              hipStream_t stream) {
    (void)in_sizes; (void)n_in; (void)out_size; (void)ws_size;
    const float* Q     = (const float*)d_in[0];
    const float* K     = (const float*)d_in[1];
    const float* Wq    = (const float*)d_in[2];
    const float* bq    = (const float*)d_in[3];
    const float* Wk    = (const float*)d_in[4];
    const float* bk    = (const float*)d_in[5];
    const float* Wv    = (const float*)d_in[6];
    const float* bv    = (const float*)d_in[7];
    const float* W1    = (const float*)d_in[8];
    const float* b1    = (const float*)d_in[9];
    const float* W2    = (const float*)d_in[10];
    const float* b2    = (const float*)d_in[11];
    const float* g0    = (const float*)d_in[12];
    const float* beta0 = (const float*)d_in[13];
    const float* g1    = (const float*)d_in[14];
    const float* beta1 = (const float*)d_in[15];

    // Workspace layout (bytes), total 32.625 MiB. Stream-ordered aliasing:
    //  [0,4)Mi   Qp bf16              -> later H1 bf16 (ffn1 after attn)
    //  [4,8)Mi   Kp bf16  \ later G fp32 [4,12)Mi (ffn2 after attn/vt)
    //  [8,12)Mi  Vp bf16  /
    //  [12,16)Mi VT bf16
    //  [16,24)Mi Opre fp32
    //  [24,32)Mi O fp32
    //  [32Mi, +640K) WT bf16 x5
    char* ws = (char*)d_ws;
    unsigned short* Qp  = (unsigned short*)(ws);
    unsigned short* Kp  = (unsigned short*)(ws + (4u  << 20));
    unsigned short* Vp  = (unsigned short*)(ws + (8u  << 20));
    unsigned short* VT  = (unsigned short*)(ws + (12u << 20));
    float*          Opre= (float*)(ws + (16u << 20));
    float*          O   = (float*)(ws + (24u << 20));
    unsigned short* WT5 = (unsigned short*)(ws + (32u << 20));
    unsigned short* H1  = Qp;
    float*          G   = (float*)(ws + (4u << 20));
    float*          out = (float*)d_out;

    const unsigned short* WTq = WT5;
    const unsigned short* WTk = WT5 + 65536;
    const unsigned short* WTv = WT5 + 2 * 65536;
    const unsigned short* WT1 = WT5 + 3 * 65536;
    const unsigned short* WT2 = WT5 + 4 * 65536;

    const int M = BB * NN;                        // 8192 rows

    wt_prep<<<dim3(4, 4, 5), 256, 0, stream>>>(Wq, Wk, Wv, W1, W2, WT5);
    gemm_mfma<0, 0><<<M / 16, 256, 0, stream>>>(Q, WTq, bq, Qp);
    gemm_mfma<0, 0><<<M / 16, 256, 0, stream>>>(K, WTk, bk, Kp);
    gemm_mfma<0, 0><<<M / 16, 256, 0, stream>>>(K, WTv, bv, Vp);
    vt_prep<<<dim3(128, 4), 256, 0, stream>>>(Vp, VT);
    attn_mfma<<<BB * HH * (NN / 64), 256, 0, stream>>>(Qp, Kp, VT, Opre);
    ln_rows<<<M, 64, 0, stream>>>(Opre, g0, beta0, O);
    gemm_mfma<0, 1><<<M / 16, 256, 0, stream>>>(O, WT1, b1, H1);
    gemm_mfma<1, 2><<<M / 16, 256, 0, stream>>>(H1, WT2, b2, G);
    add_ln<<<M, 64, 0, stream>>>(O, G, g1, beta1, out);
}

// Round 4
// 273.075 us; speedup vs baseline: 4.8028x; 1.0663x over previous
//
#include <hip/hip_runtime.h>

// MAB block, MFMA bf16, round 4: S^T-form flash attention (barrier-free
// K-loop, k-split-2 in-block), col-split GEMMs, FFN2+residual+LN fused.

typedef float fx4 __attribute__((ext_vector_type(4)));
typedef short short8 __attribute__((ext_vector_type(8)));

#define BB  4
#define NN  2048
#define DD  256
#define HH  4
#define DHH 64

__device__ __forceinline__ float bf2f(unsigned short u) {
    union { unsigned int i; float f; } v; v.i = ((unsigned int)u) << 16; return v.f;
}
__device__ __forceinline__ unsigned short f2bf(float f) {
    union { float f; unsigned int i; } v; v.f = f;
    unsigned int r = v.i + 0x7FFF + ((v.i >> 16) & 1);   // RNE
    return (unsigned short)(r >> 16);
}
__device__ __forceinline__ unsigned int fbits(float f) {
    union { float f; unsigned int i; } v; v.f = f; return v.i;
}

// ---------------------------------------------------------------------------
// Weight prep: WT[n][k] = bf16(W[k][n]) for the 5 weight matrices (256x256).
// ---------------------------------------------------------------------------
__global__ __launch_bounds__(256) void wt_prep(
        const float* __restrict__ w0, const float* __restrict__ w1,
        const float* __restrict__ w2, const float* __restrict__ w3,
        const float* __restrict__ w4, unsigned short* __restrict__ dst) {
    __shared__ unsigned short T[64 * 73];
    const int tid = threadIdx.x;
    const int z = blockIdx.z;
    const float* W = (z == 0) ? w0 : (z == 1) ? w1 : (z == 2) ? w2 : (z == 3) ? w3 : w4;
    unsigned short* WT = dst + z * 65536;
    const int nb = blockIdx.x * 64, kb = blockIdx.y * 64;
    {
        int kl = tid >> 2, c0 = (tid & 3) * 16;
        const float* src = W + (size_t)(kb + kl) * DD + nb + c0;
#pragma unroll
        for (int i = 0; i < 16; ++i) T[kl * 73 + c0 + i] = f2bf(src[i]);
    }
    __syncthreads();
    {
        int nl = tid >> 2, k0 = (tid & 3) * 16;
        short8 o0, o1;
#pragma unroll
        for (int i = 0; i < 8; ++i) {
            o0[i] = (short)T[(k0 + i) * 73 + nl];
            o1[i] = (short)T[(k0 + 8 + i) * 73 + nl];
        }
        short8* d = (short8*)(WT + (size_t)(nb + nl) * DD + kb + k0);
        d[0] = o0; d[1] = o1;
    }
}

// ---------------------------------------------------------------------------
// V transpose: VT[(b*4+h)*64 + d][key] = Vp[b*2048+key][h*64+d]. grid(128,4).
// ---------------------------------------------------------------------------
__global__ __launch_bounds__(256) void vt_prep(
        const unsigned short* __restrict__ Vp, unsigned short* __restrict__ VT) {
    __shared__ unsigned short T[64 * 73];
    const int tid = threadIdx.x;
    const int hb = blockIdx.y;
    const int b = blockIdx.x >> 5;
    const int keyb = (blockIdx.x & 31) * 64;
    {
        int kl = tid >> 2, c0 = (tid & 3) * 16;
        const short8* src = (const short8*)(Vp + (size_t)(b * NN + keyb + kl) * DD + hb * DHH + c0);
        short8 v0 = src[0], v1 = src[1];
#pragma unroll
        for (int i = 0; i < 8; ++i) {
            T[kl * 73 + c0 + i]     = (unsigned short)v0[i];
            T[kl * 73 + c0 + 8 + i] = (unsigned short)v1[i];
        }
    }
    __syncthreads();
    {
        int dl = tid >> 2, k0 = (tid & 3) * 16;
        short8 o0, o1;
#pragma unroll
        for (int i = 0; i < 8; ++i) {
            o0[i] = (short)T[(k0 + i) * 73 + dl];
            o1[i] = (short)T[(k0 + 8 + i) * 73 + dl];
        }
        short8* d = (short8*)(VT + (size_t)((b * HH + hb) * DHH + dl) * NN + keyb + k0);
        d[0] = o0; d[1] = o1;
    }
}

// ---------------------------------------------------------------------------
// MFMA GEMM, col-split: block = 16 rows x 128 cols (4 waves, wave = 16x32).
// grid = (M/16)*2.  AIN: 0 fp32 A, 1 bf16 A.  EP: 0 bias->bf16, 1 relu->bf16.
// ---------------------------------------------------------------------------
template<int AIN, int EP>
__global__ __launch_bounds__(256) void gemm_mfma(
        const void* __restrict__ Ain, const unsigned short* __restrict__ WT,
        const float* __restrict__ bias, void* __restrict__ Cout) {
    __shared__ unsigned short As[16 * 264];
    const int tid = threadIdx.x;
    const int lane = tid & 63, w = tid >> 6;
    const int l15 = lane & 15, quad = lane >> 4;
    const int r0 = (blockIdx.x >> 1) * 16;
    const int c0w = (blockIdx.x & 1) * 128 + w * 32;
    {   // stage A tile (16 x 256) as bf16
        int row = tid >> 4, c0 = (tid & 15) * 16;
        short8 o0, o1;
        if (AIN == 0) {
            const fx4* s4 = (const fx4*)((const float*)Ain + (size_t)(r0 + row) * DD + c0);
            fx4 v0 = s4[0], v1 = s4[1], v2 = s4[2], v3 = s4[3];
#pragma unroll
            for (int i = 0; i < 4; ++i) {
                o0[i]     = (short)f2bf(v0[i]); o0[i + 4] = (short)f2bf(v1[i]);
                o1[i]     = (short)f2bf(v2[i]); o1[i + 4] = (short)f2bf(v3[i]);
            }
        } else {
            const short8* s8 = (const short8*)((const unsigned short*)Ain + (size_t)(r0 + row) * DD + c0);
            o0 = s8[0]; o1 = s8[1];
        }
        short8* d = (short8*)(As + row * 264 + c0);
        d[0] = o0; d[1] = o1;
    }
    __syncthreads();
    fx4 acc[2];
#pragma unroll
    for (int i = 0; i < 2; ++i) acc[i] = (fx4){0.f, 0.f, 0.f, 0.f};
#pragma unroll
    for (int kc = 0; kc < 8; ++kc) {
        short8 a = *(const short8*)(As + l15 * 264 + kc * 32 + 8 * quad);
#pragma unroll
        for (int dt = 0; dt < 2; ++dt) {
            short8 bfr = *(const short8*)(WT + (size_t)(c0w + dt * 16 + l15) * DD + kc * 32 + 8 * quad);
            acc[dt] = __builtin_amdgcn_mfma_f32_16x16x32_bf16(a, bfr, acc[dt], 0, 0, 0);
        }
    }
    float bv[2];
#pragma unroll
    for (int dt = 0; dt < 2; ++dt) bv[dt] = bias[c0w + dt * 16 + l15];
#pragma unroll
    for (int r = 0; r < 4; ++r) {
        const size_t grow = r0 + 4 * quad + r;
#pragma unroll
        for (int dt = 0; dt < 2; ++dt) {
            const int col = c0w + dt * 16 + l15;
            float v = acc[dt][r] + bv[dt];
            if (EP == 1) v = fmaxf(v, 0.0f);
            ((unsigned short*)Cout)[grow * DD + col] = f2bf(v);
        }
    }
}

// ---------------------------------------------------------------------------
// FFN2 + residual + LayerNorm fused: out = LN(R + A@W2 + b2), fp32 out.
// Block = 16 rows x 256 cols (full rows -> block-level LN). A bf16.
// ---------------------------------------------------------------------------
__global__ __launch_bounds__(256) void gemm_ffn2_ln(
        const unsigned short* __restrict__ Ain, const unsigned short* __restrict__ WT,
        const float* __restrict__ bias, const float* __restrict__ R,
        const float* __restrict__ g, const float* __restrict__ be,
        float* __restrict__ out) {
    __shared__ unsigned short As[16 * 264];
    __shared__ float lnb[2][4][16];
    const int tid = threadIdx.x;
    const int lane = tid & 63, w = tid >> 6;
    const int l15 = lane & 15, quad = lane >> 4;
    const int r0 = blockIdx.x * 16;
    {
        int row = tid >> 4, c0 = (tid & 15) * 16;
        const short8* s8 = (const short8*)(Ain + (size_t)(r0 + row) * DD + c0);
        short8* d = (short8*)(As + row * 264 + c0);
        d[0] = s8[0]; d[1] = s8[1];
    }
    __syncthreads();
    fx4 acc[4];
#pragma unroll
    for (int i = 0; i < 4; ++i) acc[i] = (fx4){0.f, 0.f, 0.f, 0.f};
#pragma unroll
    for (int kc = 0; kc < 8; ++kc) {
        short8 a = *(const short8*)(As + l15 * 264 + kc * 32 + 8 * quad);
#pragma unroll
        for (int dt = 0; dt < 4; ++dt) {
            short8 bfr = *(const short8*)(WT + (size_t)(w * 64 + dt * 16 + l15) * DD + kc * 32 + 8 * quad);
            acc[dt] = __builtin_amdgcn_mfma_f32_16x16x32_bf16(a, bfr, acc[dt], 0, 0, 0);
        }
    }
    float bv[4], gv[4], ev[4];
#pragma unroll
    for (int dt = 0; dt < 4; ++dt) {
        int col = w * 64 + dt * 16 + l15;
        bv[dt] = bias[col]; gv[dt] = g[col]; ev[dt] = be[col];
    }
    float v[4][4], p1[4], p2[4];
#pragma unroll
    for (int r = 0; r < 4; ++r) {
        p1[r] = 0.f; p2[r] = 0.f;
        const size_t grow = r0 + 4 * quad + r;
#pragma unroll
        for (int dt = 0; dt < 4; ++dt) {
            float x = acc[dt][r] + bv[dt] + R[grow * DD + w * 64 + dt * 16 + l15];
            v[r][dt] = x; p1[r] += x; p2[r] += x * x;
        }
    }
#pragma unroll
    for (int r = 0; r < 4; ++r) {
#pragma unroll
        for (int off = 1; off <= 8; off <<= 1) {
            p1[r] += __shfl_xor(p1[r], off);
            p2[r] += __shfl_xor(p2[r], off);
        }
    }
    if (l15 == 0) {
#pragma unroll
        for (int r = 0; r < 4; ++r) {
            lnb[0][w][4 * quad + r] = p1[r];
            lnb[1][w][4 * quad + r] = p2[r];
        }
    }
    __syncthreads();
#pragma unroll
    for (int r = 0; r < 4; ++r) {
        const int row = 4 * quad + r;
        float s1 = lnb[0][0][row] + lnb[0][1][row] + lnb[0][2][row] + lnb[0][3][row];
        float s2 = lnb[1][0][row] + lnb[1][1][row] + lnb[1][2][row] + lnb[1][3][row];
        float mean = s1 * (1.0f / 256.0f);
        float var  = s2 * (1.0f / 256.0f) - mean * mean;
        float rstd = rsqrtf(var + 1e-5f);
        const size_t grow = r0 + row;
#pragma unroll
        for (int dt = 0; dt < 4; ++dt)
            out[grow * DD + w * 64 + dt * 16 + l15] = (v[r][dt] - mean) * rstd * gv[dt] + ev[dt];
    }
}

// ---------------------------------------------------------------------------
// Flash attention, S^T form, k-split-2 in block. Block = 32 q-rows, 4 waves:
// wave w -> q-subtile (w&1)*16, K-half (w>>1)*1024. Barrier-free K-loop:
// S^T = K.Q^T (C: row=key, col=q) -> per-thread softmax (q=lane&15) ->
// packed b64 P writes [q][key] -> b128 A-frag reads -> od += P.V.
// End: LDS merge of two K-halves, write Opre = attn + Qp.
// ---------------------------------------------------------------------------
__global__ __launch_bounds__(256, 4) void attn_mfma(
        const unsigned short* __restrict__ Qp, const unsigned short* __restrict__ Kp,
        const unsigned short* __restrict__ VT, float* __restrict__ Opre) {
    __shared__ unsigned short plds[4 * 16 * 76];   // per-wave P buffers (pitch 76)
    __shared__ float macc[2 * 16 * 65];            // merge area (pitch 65)
    __shared__ float mstat[2][4][16];              // [m/l][wave][q]
    const int tid = threadIdx.x;
    const int lane = tid & 63, w = tid >> 6;
    const int l15 = lane & 15, quad = lane >> 4;
    const int qs = w & 1, kh = w >> 1;
    const int qc = blockIdx.x & 63;
    const int h  = (blockIdx.x >> 6) & 3;
    const int b  = blockIdx.x >> 8;
    const int qrow = qc * 32 + qs * 16;

    short8 aq0, aq1;
    {
        const unsigned short* qptr = Qp + ((size_t)(b * NN + qrow + l15) * DD + h * DHH + 8 * quad);
        aq0 = *(const short8*)qptr;
        aq1 = *(const short8*)(qptr + 32);
    }
    fx4 od[4];
#pragma unroll
    for (int i = 0; i < 4; ++i) od[i] = (fx4){0.f, 0.f, 0.f, 0.f};
    float m = -1e30f, l = 0.0f;

    unsigned short* pl = plds + w * (16 * 76);
    const unsigned short* kbase = Kp + ((size_t)(b * NN) * DD + h * DHH + 8 * quad);
    const unsigned short* vbase = VT + ((size_t)((b * HH + h) * DHH)) * NN + 8 * quad;

    for (int t = 0; t < 16; ++t) {
        const int kt = kh * 1024 + t * 64;
        // hoisted V loads (independent of softmax)
        short8 bv0[4], bv1[4];
#pragma unroll
        for (int dt = 0; dt < 4; ++dt) {
            const unsigned short* vp = vbase + (size_t)(dt * 16 + l15) * NN + kt;
            bv0[dt] = *(const short8*)vp;
            bv1[dt] = *(const short8*)(vp + 32);
        }
        // S^T = K.Q^T : A = K-frag (m=key), B = Q-frag (n=q)
        fx4 s[4];
#pragma unroll
        for (int j = 0; j < 4; ++j) {
            const unsigned short* kp = kbase + (size_t)(kt + j * 16 + l15) * DD;
            short8 k0 = *(const short8*)kp;
            short8 k1 = *(const short8*)(kp + 32);
            fx4 a = (fx4){0.f, 0.f, 0.f, 0.f};
            a = __builtin_amdgcn_mfma_f32_16x16x32_bf16(k0, aq0, a, 0, 0, 0);
            a = __builtin_amdgcn_mfma_f32_16x16x32_bf16(k1, aq1, a, 0, 0, 0);
            s[j] = a * 0.125f;
        }
        // softmax for q = l15 (all 16 values this thread holds are one q-col)
        float tm = s[0][0];
#pragma unroll
        for (int j = 0; j < 4; ++j)
#pragma unroll
            for (int r = 0; r < 4; ++r) tm = fmaxf(tm, s[j][r]);
        tm = fmaxf(tm, __shfl_xor(tm, 16));
        tm = fmaxf(tm, __shfl_xor(tm, 32));
        float mn = fmaxf(m, tm);
        float al = __expf(m - mn);
        m = mn;
        float tl = 0.f;
#pragma unroll
        for (int j = 0; j < 4; ++j)
#pragma unroll
            for (int r = 0; r < 4; ++r) {
                float p = __expf(s[j][r] - m);
                s[j][r] = p; tl += p;
            }
        tl += __shfl_xor(tl, 16);
        tl += __shfl_xor(tl, 32);
        l = l * al + tl;
        // packed P write: [q=l15][key_local = j*16 + 4*quad + r]
#pragma unroll
        for (int j = 0; j < 4; ++j) {
            unsigned int d0 = ((fbits(s[j][0]) + 0x8000u) >> 16) | ((fbits(s[j][1]) + 0x8000u) & 0xFFFF0000u);
            unsigned int d1 = ((fbits(s[j][2]) + 0x8000u) >> 16) | ((fbits(s[j][3]) + 0x8000u) & 0xFFFF0000u);
            *(unsigned long long*)(pl + l15 * 76 + j * 16 + 4 * quad) =
                (unsigned long long)d0 | ((unsigned long long)d1 << 32);
        }
        // rescale accumulator rows (od row = q_local = 4*quad+r)
        float ar[4];
#pragma unroll
        for (int r = 0; r < 4; ++r) ar[r] = __shfl(al, 4 * quad + r);
#pragma unroll
        for (int dt = 0; dt < 4; ++dt)
#pragma unroll
            for (int r = 0; r < 4; ++r) od[dt][r] *= ar[r];
        // P A-frag (in-wave lgkm ordering; wave-private buffer, no barrier)
        short8 ap0 = *(const short8*)(pl + l15 * 76 + 8 * quad);
        short8 ap1 = *(const short8*)(pl + l15 * 76 + 32 + 8 * quad);
#pragma unroll
        for (int dt = 0; dt < 4; ++dt) {
            od[dt] = __builtin_amdgcn_mfma_f32_16x16x32_bf16(ap0, bv0[dt], od[dt], 0, 0, 0);
            od[dt] = __builtin_amdgcn_mfma_f32_16x16x32_bf16(ap1, bv1[dt], od[dt], 0, 0, 0);
        }
    }
    // ---- merge the two K-halves ----
    if (quad == 0) { mstat[0][w][l15] = m; mstat[1][w][l15] = l; }
    __syncthreads();
    {
        const int pw = w ^ 2;
        float m2 = mstat[0][pw][l15], l2 = mstat[1][pw][l15];
        float M = fmaxf(m, m2);
        float a  = __expf(m - M);
        float a2 = __expf(m2 - M);
        float L = a * l + a2 * l2;
        float c = a / L;
        float cr[4];
#pragma unroll
        for (int r = 0; r < 4; ++r) cr[r] = __shfl(c, 4 * quad + r);
#pragma unroll
        for (int dt = 0; dt < 4; ++dt)
#pragma unroll
            for (int r = 0; r < 4; ++r) od[dt][r] *= cr[r];
    }
    if (kh == 0) {
#pragma unroll
        for (int r = 0; r < 4; ++r)
#pragma unroll
            for (int dt = 0; dt < 4; ++dt)
                macc[(qs * 16 + 4 * quad + r) * 65 + dt * 16 + l15] = od[dt][r];
    }
    __syncthreads();
    if (kh == 1) {
#pragma unroll
        for (int r = 0; r < 4; ++r) {
            const size_t grow = (size_t)(b * NN) + qrow + 4 * quad + r;
#pragma unroll
            for (int dt = 0; dt < 4; ++dt) {
                const int col = h * DHH + dt * 16 + l15;
                float val = od[dt][r] + macc[(qs * 16 + 4 * quad + r) * 65 + dt * 16 + l15]
                          + bf2f(Qp[grow * DD + col]);
                Opre[grow * DD + col] = val;
            }
        }
    }
}

// row LayerNorm: Y = LN(X)*g+be (fp32)
__global__ __launch_bounds__(64) void ln_rows(
        const float* __restrict__ X, const float* __restrict__ g,
        const float* __restrict__ be, float* __restrict__ Y) {
    const int lane = threadIdx.x;
    const size_t row = blockIdx.x;
    fx4 v = ((const fx4*)(X + row * DD))[lane];
    float s1 = v[0]+v[1]+v[2]+v[3];
    float s2 = v[0]*v[0]+v[1]*v[1]+v[2]*v[2]+v[3]*v[3];
#pragma unroll
    for (int off = 32; off >= 1; off >>= 1) {
        s1 += __shfl_xor(s1, off); s2 += __shfl_xor(s2, off);
    }
    float mean = s1 * (1.0f/256.0f);
    float var  = s2 * (1.0f/256.0f) - mean * mean;
    float rstd = rsqrtf(var + 1e-5f);
    fx4 gv = ((const fx4*)g)[lane];
    fx4 ev = ((const fx4*)be)[lane];
    fx4 o;
#pragma unroll
    for (int i = 0; i < 4; ++i) o[i] = (v[i]-mean)*rstd*gv[i] + ev[i];
    ((fx4*)(Y + row * DD))[lane] = o;
}

extern "C" void kernel_launch(void* const* d_in, const int* in_sizes, int n_in,
                              void* d_out, int out_size, void* d_ws, size_t ws_size,
                              hipStream_t stream) {
    (void)in_sizes; (void)n_in; (void)out_size; (void)ws_size;
    const float* Q     = (const float*)d_in[0];
    const float* K     = (const float*)d_in[1];
    const float* Wq    = (const float*)d_in[2];
    const float* bq    = (const float*)d_in[3];
    const float* Wk    = (const float*)d_in[4];
    const float* bk    = (const float*)d_in[5];
    const float* Wv    = (const float*)d_in[6];
    const float* bv    = (const float*)d_in[7];
    const float* W1    = (const float*)d_in[8];
    const float* b1    = (const float*)d_in[9];
    const float* W2    = (const float*)d_in[10];
    const float* b2    = (const float*)d_in[11];
    const float* g0    = (const float*)d_in[12];
    const float* beta0 = (const float*)d_in[13];
    const float* g1    = (const float*)d_in[14];
    const float* beta1 = (const float*)d_in[15];

    // Workspace: [0,4)Mi Qp bf16 (later H1 bf16); [4,8)Mi Kp; [8,12)Mi Vp;
    // [12,16)Mi VT; [16,24)Mi Opre f32; [24,32)Mi O f32; [32Mi,+640K) WT x5
    char* ws = (char*)d_ws;
    unsigned short* Qp  = (unsigned short*)(ws);
    unsigned short* Kp  = (unsigned short*)(ws + (4u  << 20));
    unsigned short* Vp  = (unsigned short*)(ws + (8u  << 20));
    unsigned short* VT  = (unsigned short*)(ws + (12u << 20));
    float*          Opre= (float*)(ws + (16u << 20));
    float*          O   = (float*)(ws + (24u << 20));
    unsigned short* WT5 = (unsigned short*)(ws + (32u << 20));
    unsigned short* H1  = Qp;
    float*          out = (float*)d_out;

    const unsigned short* WTq = WT5;
    const unsigned short* WTk = WT5 + 65536;
    const unsigned short* WTv = WT5 + 2 * 65536;
    const unsigned short* WT1 = WT5 + 3 * 65536;
    const unsigned short* WT2 = WT5 + 4 * 65536;

    const int M = BB * NN;                        // 8192 rows

    wt_prep<<<dim3(4, 4, 5), 256, 0, stream>>>(Wq, Wk, Wv, W1, W2, WT5);
    gemm_mfma<0, 0><<<M / 8, 256, 0, stream>>>(Q, WTq, bq, Qp);
    gemm_mfma<0, 0><<<M / 8, 256, 0, stream>>>(K, WTk, bk, Kp);
    gemm_mfma<0, 0><<<M / 8, 256, 0, stream>>>(K, WTv, bv, Vp);
    vt_prep<<<dim3(128, 4), 256, 0, stream>>>(Vp, VT);
    attn_mfma<<<BB * HH * (NN / 32), 256, 0, stream>>>(Qp, Kp, VT, Opre);
    ln_rows<<<M, 64, 0, stream>>>(Opre, g0, beta0, O);
    gemm_mfma<0, 1><<<M / 8, 256, 0, stream>>>(O, WT1, b1, H1);
    gemm_ffn2_ln<<<M / 16, 256, 0, stream>>>(H1, WT2, b2, O, g1, beta1, out);
}